// Round 19
// baseline (73.193 us; speedup 1.0000x reference)
//
#include <hip/hip_runtime.h>
#include <hip/hip_fp8.h>

typedef __bf16 bf16;
typedef __bf16 bf16x8 __attribute__((ext_vector_type(8)));
typedef __bf16 bf16x4v __attribute__((ext_vector_type(4)));
typedef float  f32x4  __attribute__((ext_vector_type(4)));

#define NROWS 8192
#define DDIM  256
#define TAU_INV 2.0f
#define KAPPA 2.8853900817779268f   // TAU_INV * log2(e): A pre-scale so exp(s/tau) = exp2(acc)
#define LN2 0.6931471805599453f
#define EPS 1e-8f

#define AS1C(p) ((const __attribute__((address_space(1))) void*)(p))
#define AS3(p)  ((__attribute__((address_space(3))) void*)(p))

static __device__ __forceinline__ bf16x8 cvt8(f32x4 a, f32x4 b) {
  bf16x8 o;
  o[0] = (bf16)a[0]; o[1] = (bf16)a[1]; o[2] = (bf16)a[2]; o[3] = (bf16)a[3];
  o[4] = (bf16)b[0]; o[5] = (bf16)b[1]; o[6] = (bf16)b[2]; o[7] = (bf16)b[3];
  return o;
}

static __device__ __forceinline__ unsigned char f2fp8(float x) {
  __hip_fp8_e4m3 q(x);
  return (unsigned char)q.__x;
}

// ---------------- cast 4 weight matrices fp32 -> bf16 ----------------
__global__ __launch_bounds__(256) void cast4_kernel(
    const float* __restrict__ s0, const float* __restrict__ s1,
    const float* __restrict__ s2, const float* __restrict__ s3,
    bf16* __restrict__ dst) {
  const float* s = blockIdx.y == 0 ? s0 : blockIdx.y == 1 ? s1 : blockIdx.y == 2 ? s2 : s3;
  bf16* d = dst + (size_t)blockIdx.y * 65536;
  int i = blockIdx.x * 256 + threadIdx.x;
  f32x4 v = ((const f32x4*)s)[i];
  bf16x4v o;
  o[0] = (bf16)v[0]; o[1] = (bf16)v[1]; o[2] = (bf16)v[2]; o[3] = (bf16)v[3];
  ((bf16x4v*)d)[i] = o;
}

// ------- fused cast(z) + 2-layer MLP + row-normalize (8-wave, 32-row blocks) -------
// grid (NROWS/32, 2), block 512 -> 2 INDEPENDENT blocks/CU = 4 waves/SIMD
// (r9 lesson: co-resident independent blocks beat more waves in one block).
// Wave w computes output cols [w*32, w*32+32) for the block's 32 rows; bf16
// weight fragments register-prefetched one ks ahead. OUTPUT: fp8 e4m3 unit
// rows (view 0 scaled by KAPPA), stored with half-chunk swap
// tc ^ (((row>>2)&1)<<3) so lse's ds_reads are conflict-light.
__global__ __launch_bounds__(512, 1) void mlp_norm_kernel(
    const float* __restrict__ z1f, const float* __restrict__ z2f,
    const bf16* __restrict__ wq,
    const float* __restrict__ b1c, const float* __restrict__ b2c,
    const float* __restrict__ b1k, const float* __restrict__ b2k,
    unsigned char* __restrict__ outA, unsigned char* __restrict__ outB)
{
  const int view = blockIdx.y;
  const float* xf = view ? z2f : z1f;
  const bf16*  w1 = wq + (size_t)view * 131072;
  const bf16*  w2 = w1 + 65536;
  const float* b1 = view ? b1k : b1c;
  const float* b2 = view ? b2k : b2c;
  unsigned char* out = view ? outB : outA;
  const float osc = view ? 1.0f : KAPPA;

  __shared__ __align__(16) char xs[32 * 512];   // x rows, XOR-swizzled
  __shared__ __align__(16) char hs[32 * 512];   // h rows, XOR-swizzled
  __shared__ float sspart[8][32];

  const int tid  = threadIdx.x;
  const int lane = tid & 63;
  const int w    = tid >> 6;          // 0..7
  const int c    = lane & 15;
  const int g    = lane >> 4;
  const int r0   = blockIdx.x * 32;
  const int colw = w * 32;

  // fused cast of z: 32 rows x 256 cols = 1024 chunks of 8; 512 threads -> 2 iters
#pragma unroll
  for (int k = 0; k < 2; ++k) {
    int gid = k * 512 + tid;
    int row = gid >> 5, cg = gid & 31;
    const f32x4* p = (const f32x4*)(xf + (size_t)(r0 + row) * DDIM + cg * 8);
    *(bf16x8*)(xs + row * 512 + ((cg * 16) ^ ((row & 7) << 4))) = cvt8(p[0], p[1]);
  }
  __syncthreads();

  float b1v[2], b2v[2];
#pragma unroll
  for (int ct = 0; ct < 2; ++ct) {
    b1v[ct] = b1[colw + ct * 16 + c];
    b2v[ct] = b2[colw + ct * 16 + c];
  }

  const int aswz = (c & 7) << 4;
  const bf16* w1base = w1 + (size_t)(colw + c) * DDIM + g * 8;  // + ct*16*DDIM + ks*32
  const bf16* w2base = w2 + (size_t)(colw + c) * DDIM + g * 8;

  f32x4 acc[2][2];                        // [ct][mt]
  const f32x4 fz = {0.f, 0.f, 0.f, 0.f};
#pragma unroll
  for (int ct = 0; ct < 2; ++ct)
#pragma unroll
    for (int mt = 0; mt < 2; ++mt) acc[ct][mt] = fz;

  // GEMM1: h_pre = x @ W1^T ; weights prefetched one ks ahead
  bf16x8 wcur[2], wnxt[2];
#pragma unroll
  for (int ct = 0; ct < 2; ++ct)
    wcur[ct] = *(const bf16x8*)(w1base + (size_t)ct * 16 * DDIM);
#pragma unroll
  for (int ks = 0; ks < 8; ++ks) {
    if (ks < 7) {
#pragma unroll
      for (int ct = 0; ct < 2; ++ct)
        wnxt[ct] = *(const bf16x8*)(w1base + (size_t)ct * 16 * DDIM + (ks + 1) * 32);
    }
    bf16x8 af[2];
#pragma unroll
    for (int mt = 0; mt < 2; ++mt)
      af[mt] = *(const bf16x8*)(xs + (mt * 16 + c) * 512 + ((ks * 64 + g * 16) ^ aswz));
#pragma unroll
    for (int ct = 0; ct < 2; ++ct)
#pragma unroll
      for (int mt = 0; mt < 2; ++mt)
        acc[ct][mt] = __builtin_amdgcn_mfma_f32_16x16x32_bf16(af[mt], wcur[ct], acc[ct][mt], 0, 0, 0);
#pragma unroll
    for (int ct = 0; ct < 2; ++ct) wcur[ct] = wnxt[ct];
  }

  // ELU -> hs (wave writes cols colw..+32 of all 32 rows; distinct bytes per wave)
#pragma unroll
  for (int ct = 0; ct < 2; ++ct)
#pragma unroll
    for (int mt = 0; mt < 2; ++mt)
#pragma unroll
      for (int r = 0; r < 4; ++r) {
        float pre = acc[ct][mt][r] + b1v[ct];
        float h = pre > 0.0f ? pre : (__expf(pre) - 1.0f);
        int row = mt * 16 + g * 4 + r;
        int cb = (colw + ct * 16 + c) * 2;
        *(bf16*)(hs + row * 512 + (cb ^ ((row & 7) << 4))) = (bf16)h;
      }
  __syncthreads();

#pragma unroll
  for (int ct = 0; ct < 2; ++ct)
#pragma unroll
    for (int mt = 0; mt < 2; ++mt) acc[ct][mt] = fz;

  // GEMM2: z = h @ W2^T ; same prefetch discipline
#pragma unroll
  for (int ct = 0; ct < 2; ++ct)
    wcur[ct] = *(const bf16x8*)(w2base + (size_t)ct * 16 * DDIM);
#pragma unroll
  for (int ks = 0; ks < 8; ++ks) {
    if (ks < 7) {
#pragma unroll
      for (int ct = 0; ct < 2; ++ct)
        wnxt[ct] = *(const bf16x8*)(w2base + (size_t)ct * 16 * DDIM + (ks + 1) * 32);
    }
    bf16x8 af[2];
#pragma unroll
    for (int mt = 0; mt < 2; ++mt)
      af[mt] = *(const bf16x8*)(hs + (mt * 16 + c) * 512 + ((ks * 64 + g * 16) ^ aswz));
#pragma unroll
    for (int ct = 0; ct < 2; ++ct)
#pragma unroll
      for (int mt = 0; mt < 2; ++mt)
        acc[ct][mt] = __builtin_amdgcn_mfma_f32_16x16x32_bf16(af[mt], wcur[ct], acc[ct][mt], 0, 0, 0);
#pragma unroll
    for (int ct = 0; ct < 2; ++ct) wcur[ct] = wnxt[ct];
  }

  // bias + per-wave row-norm partials (sum over this wave's 32 cols)
  float ss[2][4];                         // [mt][r]
#pragma unroll
  for (int mt = 0; mt < 2; ++mt)
#pragma unroll
    for (int r = 0; r < 4; ++r) ss[mt][r] = 0.f;
#pragma unroll
  for (int ct = 0; ct < 2; ++ct)
#pragma unroll
    for (int mt = 0; mt < 2; ++mt)
#pragma unroll
      for (int r = 0; r < 4; ++r) {
        float z = acc[ct][mt][r] + b2v[ct];
        acc[ct][mt][r] = z;
        ss[mt][r] += z * z;
      }
#pragma unroll
  for (int m = 1; m < 16; m <<= 1)
#pragma unroll
    for (int mt = 0; mt < 2; ++mt)
#pragma unroll
      for (int r = 0; r < 4; ++r) ss[mt][r] += __shfl_xor(ss[mt][r], m, 64);

  if (c == 0) {
#pragma unroll
    for (int mt = 0; mt < 2; ++mt)
#pragma unroll
      for (int r = 0; r < 4; ++r) sspart[w][mt * 16 + g * 4 + r] = ss[mt][r];
  }
  __syncthreads();

#pragma unroll
  for (int mt = 0; mt < 2; ++mt)
#pragma unroll
    for (int r = 0; r < 4; ++r) {
      int row = mt * 16 + g * 4 + r;
      float s = (sspart[0][row] + sspart[1][row]) + (sspart[2][row] + sspart[3][row])
              + (sspart[4][row] + sspart[5][row]) + (sspart[6][row] + sspart[7][row]);
      float rinv = osc / sqrtf(s);
      int hswp = ((row >> 2) & 1) << 3;   // half-chunk swap (bank de-conflict)
#pragma unroll
      for (int ct = 0; ct < 2; ++ct)
        out[(size_t)(r0 + row) * DDIM + ((colw + ct * 16 + c) ^ hswp)]
            = f2fp8(acc[ct][mt][r] * rinv);
    }
}

// ------- 128x128 tile LSE, fp8, double-buffered with counted vmcnt (r17) -------
// grid (64, 64), block 256 (4 waves, 2x2 of 64x64). LDS 32 KB: 2 bufs x
// (A 8KB | B 8KB). Per kt: barrier -> STAGE(kt+1) -> vmcnt(4) -> barrier ->
// compute. Swizzle: 16B-chunk q^=(row&3) + producer half-swap.
// A is KAPPA-prescaled -> epilogue sum += exp2(acc); diag extracted on bx==by.
__global__ __launch_bounds__(256, 2) void lse_kernel(
    const unsigned char* __restrict__ A, const unsigned char* __restrict__ B,
    float* __restrict__ partial, float* __restrict__ diagdot)
{
  __shared__ __align__(16) char lds[32768];

  const int tid  = threadIdx.x;
  const int lane = tid & 63;
  const int w    = tid >> 6;
  const int c    = lane & 15;
  const int g    = lane >> 4;
  const int brow = blockIdx.y * 128;
  const int bcol = blockIdx.x * 128;
  const int wrow = (w >> 1) * 64;
  const int wcol = (w & 1) * 64;

#define STAGE(ttt)                                                                   \
  {                                                                                  \
    const int bsel_ = ((ttt) & 1) * 16384;                                           \
    _Pragma("unroll")                                                                \
    for (int it = 0; it < 2; ++it) {                                                 \
      int slot = it * 256 + tid;                                                     \
      int row = slot >> 2, q = slot & 3;                                             \
      int col = (ttt) * 64 + ((q ^ (row & 3)) << 4);                                 \
      __builtin_amdgcn_global_load_lds(AS1C(A + (size_t)(brow + row) * DDIM + col),  \
                                       AS3(lds + bsel_ + slot * 16), 16, 0, 0);      \
      __builtin_amdgcn_global_load_lds(AS1C(B + (size_t)(bcol + row) * DDIM + col),  \
                                       AS3(lds + bsel_ + 8192 + slot * 16), 16, 0, 0); \
    }                                                                                \
  }

  f32x4 acc[4][4];
  const f32x4 fz = {0.f, 0.f, 0.f, 0.f};
#pragma unroll
  for (int i = 0; i < 4; ++i)
#pragma unroll
    for (int j = 0; j < 4; ++j) acc[i][j] = fz;

  STAGE(0);  // 4 loads in flight

#pragma unroll
  for (int kt = 0; kt < 4; ++kt) {
    __builtin_amdgcn_s_barrier();
    asm volatile("" ::: "memory");
    if (kt < 3) {
      STAGE(kt + 1);                                   // outstanding -> 8
      asm volatile("s_waitcnt vmcnt(4)" ::: "memory"); // tile kt landed
    } else {
      asm volatile("s_waitcnt vmcnt(0)" ::: "memory");
    }
    __builtin_amdgcn_s_barrier();                      // tile kt visible to all
    asm volatile("" ::: "memory");

    const char* As = lds + (kt & 1) * 16384;
    const char* Bs = As + 8192;
#pragma unroll
    for (int sk = 0; sk < 2; ++sk) {
      long af[4], bfv[4];
#pragma unroll
      for (int mt = 0; mt < 4; ++mt) {
        int rl = wrow + mt * 16 + c;
        af[mt] = *(const long*)(As + rl * 64
                  + ((((sk << 1) | (g >> 1)) ^ (rl & 3)) << 4)
                  + (((g & 1) ^ ((rl >> 2) & 1)) << 3));
      }
#pragma unroll
      for (int ct = 0; ct < 4; ++ct) {
        int rl = wcol + ct * 16 + c;
        bfv[ct] = *(const long*)(Bs + rl * 64
                  + ((((sk << 1) | (g >> 1)) ^ (rl & 3)) << 4)
                  + (((g & 1) ^ ((rl >> 2) & 1)) << 3));
      }
#pragma unroll
      for (int mt = 0; mt < 4; ++mt)
#pragma unroll
        for (int ct = 0; ct < 4; ++ct)
          acc[mt][ct] = __builtin_amdgcn_mfma_f32_16x16x32_fp8_fp8(af[mt], bfv[ct], acc[mt][ct], 0, 0, 0);
    }
  }
#undef STAGE

  // diag: bx==by blocks, waves 0/3 (wrow==wcol), tiles ct==mt, lanes c==g*4+r
  if (blockIdx.x == blockIdx.y && (w == 0 || w == 3) && (c >> 2) == g) {
#pragma unroll
    for (int mt = 0; mt < 4; ++mt) {
      f32x4 a = acc[mt][mt];
      int r = c & 3;
      float dv = (r == 0) ? a[0] : (r == 1) ? a[1] : (r == 2) ? a[2] : a[3];
      diagdot[brow + wrow + mt * 16 + c] = dv;
    }
  }

  // epilogue: exp2(acc) (A pre-scaled by KAPPA), reduce over this wave's 64 cols
  float rs[4][4];
#pragma unroll
  for (int mt = 0; mt < 4; ++mt)
#pragma unroll
    for (int r = 0; r < 4; ++r) rs[mt][r] = 0.f;
#pragma unroll
  for (int mt = 0; mt < 4; ++mt)
#pragma unroll
    for (int ct = 0; ct < 4; ++ct)
#pragma unroll
      for (int r = 0; r < 4; ++r) rs[mt][r] += __builtin_amdgcn_exp2f(acc[mt][ct][r]);
#pragma unroll
  for (int m = 1; m < 16; m <<= 1)
#pragma unroll
    for (int mt = 0; mt < 4; ++mt)
#pragma unroll
      for (int r = 0; r < 4; ++r) rs[mt][r] += __shfl_xor(rs[mt][r], m, 64);

  if (c == 0) {
    int cb2 = blockIdx.x * 2 + (w & 1);
#pragma unroll
    for (int mt = 0; mt < 4; ++mt)
#pragma unroll
      for (int r = 0; r < 4; ++r) {
        int grow = brow + wrow + mt * 16 + g * 4 + r;
        partial[(size_t)grow * 128 + cb2] = rs[mt][r];
      }
  }
}

// ------- per-row: sum 128 partials + log - diag; 4 threads/row, block sums -------
__global__ __launch_bounds__(256) void rowfinal_kernel(
    const float* __restrict__ partial, const float* __restrict__ diagdot,
    float* __restrict__ blocksum)
{
  int gid = blockIdx.x * 256 + threadIdx.x;
  int row = gid >> 2, q = gid & 3;
  const f32x4* p = (const f32x4*)(partial + (size_t)row * 128 + q * 32);
  float s = 0.f;
#pragma unroll
  for (int i = 0; i < 8; ++i) {
    f32x4 v = p[i];
    s += (v[0] + v[1]) + (v[2] + v[3]);
  }
  s += __shfl_xor(s, 1, 64);
  s += __shfl_xor(s, 2, 64);
  // diagdot = kappa * s_ii ; s_ii * TAU_INV = diagdot * ln2
  float term = (q == 0) ? (logf(s + EPS) - diagdot[row] * LN2) : 0.f;
#pragma unroll
  for (int m = 1; m < 64; m <<= 1) term += __shfl_xor(term, m, 64);
  __shared__ float part[4];
  if ((threadIdx.x & 63) == 0) part[threadIdx.x >> 6] = term;
  __syncthreads();
  if (threadIdx.x == 0) blocksum[blockIdx.x] = part[0] + part[1] + part[2] + part[3];
}

// ---------------- final mean over 128 block sums ----------------
__global__ __launch_bounds__(128) void final_kernel(const float* __restrict__ blocksum,
                                                    float* __restrict__ out)
{
  int tid = threadIdx.x;
  float s = blocksum[tid];
#pragma unroll
  for (int m = 1; m < 64; m <<= 1) s += __shfl_xor(s, m, 64);
  __shared__ float p[2];
  if ((tid & 63) == 0) p[tid >> 6] = s;
  __syncthreads();
  if (tid == 0) out[0] = (p[0] + p[1]) * (1.0f / NROWS);
}

extern "C" void kernel_launch(void* const* d_in, const int* in_sizes, int n_in,
                              void* d_out, int out_size, void* d_ws, size_t ws_size,
                              hipStream_t stream) {
  const float* z1  = (const float*)d_in[0];
  const float* z2  = (const float*)d_in[1];
  const float* W1c = (const float*)d_in[2];
  const float* b1c = (const float*)d_in[3];
  const float* W2c = (const float*)d_in[4];
  const float* b2c = (const float*)d_in[5];
  const float* W1k = (const float*)d_in[6];
  const float* b1k = (const float*)d_in[7];
  const float* W2k = (const float*)d_in[8];
  const float* b2k = (const float*)d_in[9];

  char* ws = (char*)d_ws;
  unsigned char* aU = (unsigned char*)(ws);                    // 2 MB fp8
  unsigned char* bU = (unsigned char*)(ws + (size_t)2 * 1024 * 1024);
  float* partial  = (float*)(ws + (size_t)4  * 1024 * 1024);   // 8192*128 f32 = 4 MB
  float* diagdot  = (float*)(ws + (size_t)8  * 1024 * 1024);   // 32 KB
  float* blocksum = (float*)(ws + (size_t)8  * 1024 * 1024 + 64 * 1024);
  bf16*  wq       = (bf16*)(ws + (size_t)9  * 1024 * 1024);    // 512 KB

  cast4_kernel<<<dim3(64, 4), 256, 0, stream>>>(W1c, W2c, W1k, W2k, wq);

  mlp_norm_kernel<<<dim3(NROWS / 32, 2), 512, 0, stream>>>(
      z1, z2, wq, b1c, b2c, b1k, b2k, aU, bU);

  lse_kernel<<<dim3(NROWS / 128, NROWS / 128), 256, 0, stream>>>(aU, bU, partial, diagdot);

  rowfinal_kernel<<<128, 256, 0, stream>>>(partial, diagdot, blocksum);
  final_kernel<<<1, 128, 0, stream>>>(blocksum, (float*)d_out);
}

// Round 20
// 67.984 us; speedup vs baseline: 1.0766x; 1.0766x over previous
//
#include <hip/hip_runtime.h>
#include <hip/hip_fp8.h>

typedef __bf16 bf16;
typedef __bf16 bf16x8 __attribute__((ext_vector_type(8)));
typedef __bf16 bf16x4v __attribute__((ext_vector_type(4)));
typedef float  f32x4  __attribute__((ext_vector_type(4)));

#define NROWS 8192
#define DDIM  256
#define TAU_INV 2.0f
#define KAPPA 2.8853900817779268f   // TAU_INV * log2(e): A pre-scale so exp(s/tau) = exp2(acc)
#define LN2 0.6931471805599453f
#define EPS 1e-8f

#define AS1C(p) ((const __attribute__((address_space(1))) void*)(p))
#define AS3(p)  ((__attribute__((address_space(3))) void*)(p))

static __device__ __forceinline__ bf16x8 cvt8(f32x4 a, f32x4 b) {
  bf16x8 o;
  o[0] = (bf16)a[0]; o[1] = (bf16)a[1]; o[2] = (bf16)a[2]; o[3] = (bf16)a[3];
  o[4] = (bf16)b[0]; o[5] = (bf16)b[1]; o[6] = (bf16)b[2]; o[7] = (bf16)b[3];
  return o;
}

static __device__ __forceinline__ unsigned char f2fp8(float x) {
  __hip_fp8_e4m3 q(x);
  return (unsigned char)q.__x;
}

// ---------------- cast 4 weight matrices fp32 -> bf16 ----------------
__global__ __launch_bounds__(256) void cast4_kernel(
    const float* __restrict__ s0, const float* __restrict__ s1,
    const float* __restrict__ s2, const float* __restrict__ s3,
    bf16* __restrict__ dst) {
  const float* s = blockIdx.y == 0 ? s0 : blockIdx.y == 1 ? s1 : blockIdx.y == 2 ? s2 : s3;
  bf16* d = dst + (size_t)blockIdx.y * 65536;
  int i = blockIdx.x * 256 + threadIdx.x;
  f32x4 v = ((const f32x4*)s)[i];
  bf16x4v o;
  o[0] = (bf16)v[0]; o[1] = (bf16)v[1]; o[2] = (bf16)v[2]; o[3] = (bf16)v[3];
  ((bf16x4v*)d)[i] = o;
}

// ------- fused cast(z) + 2-layer MLP + row-normalize (8-wave ct-split) -------
// grid (NROWS/64, 2), block 512 (8 waves -> 2 waves/SIMD at 1 block/CU).
// Wave w computes output cols [w*32, w*32+32) for ALL 64 rows; bf16 weight
// fragments register-prefetched one ks ahead. OUTPUT: fp8 e4m3 unit rows
// (view 0 scaled by KAPPA), stored with half-chunk swap tc ^ (((row>>2)&1)<<3)
// so lse's ds_reads are 2-way (free) instead of 4-way conflicted.
__global__ __launch_bounds__(512, 1) void mlp_norm_kernel(
    const float* __restrict__ z1f, const float* __restrict__ z2f,
    const bf16* __restrict__ wq,
    const float* __restrict__ b1c, const float* __restrict__ b2c,
    const float* __restrict__ b1k, const float* __restrict__ b2k,
    unsigned char* __restrict__ outA, unsigned char* __restrict__ outB)
{
  const int view = blockIdx.y;
  const float* xf = view ? z2f : z1f;
  const bf16*  w1 = wq + (size_t)view * 131072;
  const bf16*  w2 = w1 + 65536;
  const float* b1 = view ? b1k : b1c;
  const float* b2 = view ? b2k : b2c;
  unsigned char* out = view ? outB : outA;
  const float osc = view ? 1.0f : KAPPA;

  __shared__ __align__(16) char xs[64 * 512];   // x rows, XOR-swizzled
  __shared__ __align__(16) char hs[64 * 512];   // h rows, XOR-swizzled
  __shared__ float sspart[8][64];

  const int tid  = threadIdx.x;
  const int lane = tid & 63;
  const int w    = tid >> 6;          // 0..7
  const int c    = lane & 15;
  const int g    = lane >> 4;
  const int r0   = blockIdx.x * 64;
  const int colw = w * 32;

  // fused cast of z: 64 rows x 256 cols, 2048 groups of 8, 512 threads -> 4 iters
#pragma unroll
  for (int k = 0; k < 4; ++k) {
    int gid = k * 512 + tid;
    int row = gid >> 5, cg = gid & 31;
    const f32x4* p = (const f32x4*)(xf + (size_t)(r0 + row) * DDIM + cg * 8);
    *(bf16x8*)(xs + row * 512 + ((cg * 16) ^ ((row & 7) << 4))) = cvt8(p[0], p[1]);
  }
  __syncthreads();

  float b1v[2], b2v[2];
#pragma unroll
  for (int ct = 0; ct < 2; ++ct) {
    b1v[ct] = b1[colw + ct * 16 + c];
    b2v[ct] = b2[colw + ct * 16 + c];
  }

  const int aswz = (c & 7) << 4;
  const bf16* w1base = w1 + (size_t)(colw + c) * DDIM + g * 8;  // + ct*16*DDIM + ks*32
  const bf16* w2base = w2 + (size_t)(colw + c) * DDIM + g * 8;

  f32x4 acc[2][4];                        // [ct][mt]
  const f32x4 fz = {0.f, 0.f, 0.f, 0.f};
#pragma unroll
  for (int ct = 0; ct < 2; ++ct)
#pragma unroll
    for (int mt = 0; mt < 4; ++mt) acc[ct][mt] = fz;

  // GEMM1: h_pre = x @ W1^T ; weights prefetched one ks ahead
  bf16x8 wcur[2], wnxt[2];
#pragma unroll
  for (int ct = 0; ct < 2; ++ct)
    wcur[ct] = *(const bf16x8*)(w1base + (size_t)ct * 16 * DDIM);
#pragma unroll
  for (int ks = 0; ks < 8; ++ks) {
    if (ks < 7) {
#pragma unroll
      for (int ct = 0; ct < 2; ++ct)
        wnxt[ct] = *(const bf16x8*)(w1base + (size_t)ct * 16 * DDIM + (ks + 1) * 32);
    }
    bf16x8 af[4];
#pragma unroll
    for (int mt = 0; mt < 4; ++mt)
      af[mt] = *(const bf16x8*)(xs + (mt * 16 + c) * 512 + ((ks * 64 + g * 16) ^ aswz));
#pragma unroll
    for (int ct = 0; ct < 2; ++ct)
#pragma unroll
      for (int mt = 0; mt < 4; ++mt)
        acc[ct][mt] = __builtin_amdgcn_mfma_f32_16x16x32_bf16(af[mt], wcur[ct], acc[ct][mt], 0, 0, 0);
#pragma unroll
    for (int ct = 0; ct < 2; ++ct) wcur[ct] = wnxt[ct];
  }

  // ELU -> hs (wave writes cols colw..+32 of all rows; distinct bytes per wave)
#pragma unroll
  for (int ct = 0; ct < 2; ++ct)
#pragma unroll
    for (int mt = 0; mt < 4; ++mt)
#pragma unroll
      for (int r = 0; r < 4; ++r) {
        float pre = acc[ct][mt][r] + b1v[ct];
        float h = pre > 0.0f ? pre : (__expf(pre) - 1.0f);
        int row = mt * 16 + g * 4 + r;
        int cb = (colw + ct * 16 + c) * 2;
        *(bf16*)(hs + row * 512 + (cb ^ ((row & 7) << 4))) = (bf16)h;
      }
  __syncthreads();

#pragma unroll
  for (int ct = 0; ct < 2; ++ct)
#pragma unroll
    for (int mt = 0; mt < 4; ++mt) acc[ct][mt] = fz;

  // GEMM2: z = h @ W2^T ; same prefetch discipline
#pragma unroll
  for (int ct = 0; ct < 2; ++ct)
    wcur[ct] = *(const bf16x8*)(w2base + (size_t)ct * 16 * DDIM);
#pragma unroll
  for (int ks = 0; ks < 8; ++ks) {
    if (ks < 7) {
#pragma unroll
      for (int ct = 0; ct < 2; ++ct)
        wnxt[ct] = *(const bf16x8*)(w2base + (size_t)ct * 16 * DDIM + (ks + 1) * 32);
    }
    bf16x8 af[4];
#pragma unroll
    for (int mt = 0; mt < 4; ++mt)
      af[mt] = *(const bf16x8*)(hs + (mt * 16 + c) * 512 + ((ks * 64 + g * 16) ^ aswz));
#pragma unroll
    for (int ct = 0; ct < 2; ++ct)
#pragma unroll
      for (int mt = 0; mt < 4; ++mt)
        acc[ct][mt] = __builtin_amdgcn_mfma_f32_16x16x32_bf16(af[mt], wcur[ct], acc[ct][mt], 0, 0, 0);
#pragma unroll
    for (int ct = 0; ct < 2; ++ct) wcur[ct] = wnxt[ct];
  }

  // bias + per-wave row-norm partials (sum over this wave's 32 cols)
  float ss[4][4];                         // [mt][r]
#pragma unroll
  for (int mt = 0; mt < 4; ++mt)
#pragma unroll
    for (int r = 0; r < 4; ++r) ss[mt][r] = 0.f;
#pragma unroll
  for (int ct = 0; ct < 2; ++ct)
#pragma unroll
    for (int mt = 0; mt < 4; ++mt)
#pragma unroll
      for (int r = 0; r < 4; ++r) {
        float z = acc[ct][mt][r] + b2v[ct];
        acc[ct][mt][r] = z;
        ss[mt][r] += z * z;
      }
#pragma unroll
  for (int m = 1; m < 16; m <<= 1)
#pragma unroll
    for (int mt = 0; mt < 4; ++mt)
#pragma unroll
      for (int r = 0; r < 4; ++r) ss[mt][r] += __shfl_xor(ss[mt][r], m, 64);

  if (c == 0) {
#pragma unroll
    for (int mt = 0; mt < 4; ++mt)
#pragma unroll
      for (int r = 0; r < 4; ++r) sspart[w][mt * 16 + g * 4 + r] = ss[mt][r];
  }
  __syncthreads();

#pragma unroll
  for (int mt = 0; mt < 4; ++mt)
#pragma unroll
    for (int r = 0; r < 4; ++r) {
      int row = mt * 16 + g * 4 + r;
      float s = (sspart[0][row] + sspart[1][row]) + (sspart[2][row] + sspart[3][row])
              + (sspart[4][row] + sspart[5][row]) + (sspart[6][row] + sspart[7][row]);
      float rinv = osc / sqrtf(s);
      int hswp = ((row >> 2) & 1) << 3;   // half-chunk swap (bank de-conflict)
#pragma unroll
      for (int ct = 0; ct < 2; ++ct)
        out[(size_t)(r0 + row) * DDIM + ((colw + ct * 16 + c) ^ hswp)]
            = f2fp8(acc[ct][mt][r] * rinv);
    }
}

// ------- 128x128 tile LSE, fp8, double-buffered with counted vmcnt -------
// grid (64, 64), block 256 (4 waves, 2x2 of 64x64). LDS 32 KB: 2 bufs x
// (A 8KB | B 8KB). Per kt: barrier (prev reads done) -> STAGE(kt+1) ->
// vmcnt(4) (kt's 4 loads landed; kt+1's in flight across compute) ->
// barrier -> compute. Swizzle: 16B-chunk q^=(row&3) + producer half-swap;
// reads 2-way (free). A KAPPA-prescaled -> exp2 direct; diag on bx==by.
__global__ __launch_bounds__(256, 2) void lse_kernel(
    const unsigned char* __restrict__ A, const unsigned char* __restrict__ B,
    float* __restrict__ partial, float* __restrict__ diagdot)
{
  __shared__ __align__(16) char lds[32768];

  const int tid  = threadIdx.x;
  const int lane = tid & 63;
  const int w    = tid >> 6;
  const int c    = lane & 15;
  const int g    = lane >> 4;
  const int brow = blockIdx.y * 128;
  const int bcol = blockIdx.x * 128;
  const int wrow = (w >> 1) * 64;
  const int wcol = (w & 1) * 64;

#define STAGE(ttt)                                                                   \
  {                                                                                  \
    const int bsel_ = ((ttt) & 1) * 16384;                                           \
    _Pragma("unroll")                                                                \
    for (int it = 0; it < 2; ++it) {                                                 \
      int slot = it * 256 + tid;                                                     \
      int row = slot >> 2, q = slot & 3;                                             \
      int col = (ttt) * 64 + ((q ^ (row & 3)) << 4);                                 \
      __builtin_amdgcn_global_load_lds(AS1C(A + (size_t)(brow + row) * DDIM + col),  \
                                       AS3(lds + bsel_ + slot * 16), 16, 0, 0);      \
      __builtin_amdgcn_global_load_lds(AS1C(B + (size_t)(bcol + row) * DDIM + col),  \
                                       AS3(lds + bsel_ + 8192 + slot * 16), 16, 0, 0); \
    }                                                                                \
  }

  f32x4 acc[4][4];
  const f32x4 fz = {0.f, 0.f, 0.f, 0.f};
#pragma unroll
  for (int i = 0; i < 4; ++i)
#pragma unroll
    for (int j = 0; j < 4; ++j) acc[i][j] = fz;

  STAGE(0);  // 4 loads in flight

#pragma unroll
  for (int kt = 0; kt < 4; ++kt) {
    // all waves finished reading buf[(kt+1)&1] (tile kt-1's compute)
    __builtin_amdgcn_s_barrier();
    asm volatile("" ::: "memory");
    if (kt < 3) {
      STAGE(kt + 1);                                   // outstanding -> 8
      asm volatile("s_waitcnt vmcnt(4)" ::: "memory"); // tile kt landed
    } else {
      asm volatile("s_waitcnt vmcnt(0)" ::: "memory");
    }
    __builtin_amdgcn_s_barrier();                      // tile kt visible to all
    asm volatile("" ::: "memory");

    const char* As = lds + (kt & 1) * 16384;
    const char* Bs = As + 8192;
#pragma unroll
    for (int sk = 0; sk < 2; ++sk) {
      long af[4], bfv[4];
#pragma unroll
      for (int mt = 0; mt < 4; ++mt) {
        int rl = wrow + mt * 16 + c;
        af[mt] = *(const long*)(As + rl * 64
                  + ((((sk << 1) | (g >> 1)) ^ (rl & 3)) << 4)
                  + (((g & 1) ^ ((rl >> 2) & 1)) << 3));
      }
#pragma unroll
      for (int ct = 0; ct < 4; ++ct) {
        int rl = wcol + ct * 16 + c;
        bfv[ct] = *(const long*)(Bs + rl * 64
                  + ((((sk << 1) | (g >> 1)) ^ (rl & 3)) << 4)
                  + (((g & 1) ^ ((rl >> 2) & 1)) << 3));
      }
#pragma unroll
      for (int mt = 0; mt < 4; ++mt)
#pragma unroll
        for (int ct = 0; ct < 4; ++ct)
          acc[mt][ct] = __builtin_amdgcn_mfma_f32_16x16x32_fp8_fp8(af[mt], bfv[ct], acc[mt][ct], 0, 0, 0);
    }
  }
#undef STAGE

  // diag: bx==by blocks, waves 0/3 (wrow==wcol), tiles ct==mt, lanes c==g*4+r
  if (blockIdx.x == blockIdx.y && (w == 0 || w == 3) && (c >> 2) == g) {
#pragma unroll
    for (int mt = 0; mt < 4; ++mt) {
      f32x4 a = acc[mt][mt];
      int r = c & 3;
      float dv = (r == 0) ? a[0] : (r == 1) ? a[1] : (r == 2) ? a[2] : a[3];
      diagdot[brow + wrow + mt * 16 + c] = dv;
    }
  }

  // epilogue: exp2(acc) (A pre-scaled by KAPPA), reduce over this wave's 64 cols
  float rs[4][4];
#pragma unroll
  for (int mt = 0; mt < 4; ++mt)
#pragma unroll
    for (int r = 0; r < 4; ++r) rs[mt][r] = 0.f;
#pragma unroll
  for (int mt = 0; mt < 4; ++mt)
#pragma unroll
    for (int ct = 0; ct < 4; ++ct)
#pragma unroll
      for (int r = 0; r < 4; ++r) rs[mt][r] += __builtin_amdgcn_exp2f(acc[mt][ct][r]);
#pragma unroll
  for (int m = 1; m < 16; m <<= 1)
#pragma unroll
    for (int mt = 0; mt < 4; ++mt)
#pragma unroll
      for (int r = 0; r < 4; ++r) rs[mt][r] += __shfl_xor(rs[mt][r], m, 64);

  if (c == 0) {
    int cb2 = blockIdx.x * 2 + (w & 1);
#pragma unroll
    for (int mt = 0; mt < 4; ++mt)
#pragma unroll
      for (int r = 0; r < 4; ++r) {
        int grow = brow + wrow + mt * 16 + g * 4 + r;
        partial[(size_t)grow * 128 + cb2] = rs[mt][r];
      }
  }
}

// ------- per-row: sum 128 partials + log - diag; 4 threads/row, block sums -------
__global__ __launch_bounds__(256) void rowfinal_kernel(
    const float* __restrict__ partial, const float* __restrict__ diagdot,
    float* __restrict__ blocksum)
{
  int gid = blockIdx.x * 256 + threadIdx.x;
  int row = gid >> 2, q = gid & 3;
  const f32x4* p = (const f32x4*)(partial + (size_t)row * 128 + q * 32);
  float s = 0.f;
#pragma unroll
  for (int i = 0; i < 8; ++i) {
    f32x4 v = p[i];
    s += (v[0] + v[1]) + (v[2] + v[3]);
  }
  s += __shfl_xor(s, 1, 64);
  s += __shfl_xor(s, 2, 64);
  // diagdot = kappa * s_ii ; s_ii * TAU_INV = diagdot * ln2
  float term = (q == 0) ? (logf(s + EPS) - diagdot[row] * LN2) : 0.f;
#pragma unroll
  for (int m = 1; m < 64; m <<= 1) term += __shfl_xor(term, m, 64);
  __shared__ float part[4];
  if ((threadIdx.x & 63) == 0) part[threadIdx.x >> 6] = term;
  __syncthreads();
  if (threadIdx.x == 0) blocksum[blockIdx.x] = part[0] + part[1] + part[2] + part[3];
}

// ---------------- final mean over 128 block sums ----------------
__global__ __launch_bounds__(128) void final_kernel(const float* __restrict__ blocksum,
                                                    float* __restrict__ out)
{
  int tid = threadIdx.x;
  float s = blocksum[tid];
#pragma unroll
  for (int m = 1; m < 64; m <<= 1) s += __shfl_xor(s, m, 64);
  __shared__ float p[2];
  if ((tid & 63) == 0) p[tid >> 6] = s;
  __syncthreads();
  if (tid == 0) out[0] = (p[0] + p[1]) * (1.0f / NROWS);
}

extern "C" void kernel_launch(void* const* d_in, const int* in_sizes, int n_in,
                              void* d_out, int out_size, void* d_ws, size_t ws_size,
                              hipStream_t stream) {
  const float* z1  = (const float*)d_in[0];
  const float* z2  = (const float*)d_in[1];
  const float* W1c = (const float*)d_in[2];
  const float* b1c = (const float*)d_in[3];
  const float* W2c = (const float*)d_in[4];
  const float* b2c = (const float*)d_in[5];
  const float* W1k = (const float*)d_in[6];
  const float* b1k = (const float*)d_in[7];
  const float* W2k = (const float*)d_in[8];
  const float* b2k = (const float*)d_in[9];

  char* ws = (char*)d_ws;
  unsigned char* aU = (unsigned char*)(ws);                    // 2 MB fp8
  unsigned char* bU = (unsigned char*)(ws + (size_t)2 * 1024 * 1024);
  float* partial  = (float*)(ws + (size_t)4  * 1024 * 1024);   // 8192*128 f32 = 4 MB
  float* diagdot  = (float*)(ws + (size_t)8  * 1024 * 1024);   // 32 KB
  float* blocksum = (float*)(ws + (size_t)8  * 1024 * 1024 + 64 * 1024);
  bf16*  wq       = (bf16*)(ws + (size_t)9  * 1024 * 1024);    // 512 KB

  cast4_kernel<<<dim3(64, 4), 256, 0, stream>>>(W1c, W2c, W1k, W2k, wq);

  mlp_norm_kernel<<<dim3(NROWS / 64, 2), 512, 0, stream>>>(
      z1, z2, wq, b1c, b2c, b1k, b2k, aU, bU);

  lse_kernel<<<dim3(NROWS / 128, NROWS / 128), 256, 0, stream>>>(aU, bU, partial, diagdot);

  rowfinal_kernel<<<128, 256, 0, stream>>>(partial, diagdot, blocksum);
  final_kernel<<<1, 128, 0, stream>>>(blocksum, (float*)d_out);
}